// Round 13
// baseline (202.126 us; speedup 1.0000x reference)
//
#include <hip/hip_runtime.h>

typedef _Float16 hf;
typedef _Float16 half2v __attribute__((ext_vector_type(2)));
typedef _Float16 half4 __attribute__((ext_vector_type(4)));
typedef _Float16 half8 __attribute__((ext_vector_type(8)));
typedef float f32x4 __attribute__((ext_vector_type(4)));

constexpr int Steps = 27;

// wsh half-index layout (prep output; xWb ELIMINATED -- witran computes x-gates in-step):
//   wrec : [0, 393216)         (((cls*16+wv16)*3+j)*8+ks)*512 + lane*8 + jj
//   wx   : [393216, 589824)    (((cls*6+g)*8+wv)*4+ks)*512 + lane*8 + j   K=[256,384)
//   fc3  : [589824, 598016)
//   fc4  : [598016, 614400)
constexpr int OFF_WX = 393216;
constexpr int OFF_F3 = 589824;
constexpr int OFF_F4 = 598016;
constexpr int OFF_XW = 614400;

// witran smem layout (halfs). h persists through the recurrence; R region is
// time-shared: prologue {xA, hbuf1} -> recurrence {A[2], wlds}.
constexpr int H_OFF = 0;                  // h: 193 rows x 128 (row 192 = zrow)
constexpr int R_OFF = 24704;
constexpr int XA_OFF = R_OFF;             // prologue: x staging 192x64
constexpr int H1_OFF = R_OFF + 12288;     // prologue: fc3 out 192x128
constexpr int A0_OFF = R_OFF;             // recurrence: A[0] 16x256
constexpr int A1_OFF = R_OFF + 4096;      // A[1]
constexpr int WL_OFF = R_OFF + 8192;      // i_c Wrec frags, 8 waves x 4096
constexpr int SM_HALFS = R_OFF + 40960;   // 65664 halfs = 131328 B

__device__ __forceinline__ int aidx(int r, int k) {  // halfs, K=256 (witran A)
  int blk = k >> 3;
  return r * 256 + (((blk ^ (r & 7)) & 31) << 3) + (k & 7);
}
__device__ __forceinline__ int hidx(int r, int k) {  // halfs, K=128 (h buffers)
  int blk = k >> 3;
  return r * 128 + (((blk ^ (r & 15)) & 15) << 3) + (k & 7);
}
__device__ __forceinline__ int xidx(int r, int k) {  // halfs, K=64 (x staging)
  int blk = k >> 3;
  return r * 64 + (((blk ^ (r & 7)) & 7) << 3) + (k & 7);
}
__device__ __forceinline__ float rcpf_(float x) { return __builtin_amdgcn_rcpf(x); }
__device__ __forceinline__ float sigmoidf_(float x) { return rcpf_(1.0f + __expf(-x)); }
__device__ __forceinline__ float tanh_(float x) { return 1.0f - 2.0f * rcpf_(__expf(2.0f * x) + 1.0f); }

// Hardened lgkm-only barrier (R12-proven): returns an SGPR zero produced BY the barrier
// asm; post-barrier LDS pointers are offset by it (data dependency = no hoisting), and
// there is NO "memory" clobber (no vmcnt drain; R9's -12us). The zero also makes the
// per-step Wx global-load addresses loop-variant, preventing LICM from hoisting 24
// half8 loads into registers (which would blow the 256-reg budget).
__device__ __forceinline__ int bar_dep() {
  int z;
  __builtin_amdgcn_sched_barrier(0);
  asm volatile("s_waitcnt lgkmcnt(0)\n\ts_barrier\n\ts_mov_b32 %0, 0" : "=s"(z));
  __builtin_amdgcn_sched_barrier(0);
  return z;
}

// ---- kernel 1: all weights -> fragment-ordered fp16 (unchanged from R12) ----
__global__ __launch_bounds__(512) void prep(const float* __restrict__ fc3_w,
                                            const float* __restrict__ fc4_w,
                                            const float* __restrict__ W_enc,
                                            hf* __restrict__ wsh) {
  int idx = (blockIdx.x * 512 + threadIdx.x) * 8;  // base of 8-chunk
  if (idx >= OFF_XW) return;
  const float* src;
  if (idx < OFF_WX) {  // recurrent W, gate-triple per wave-block
    int lane = (idx >> 3) & 63, rest = idx >> 9;
    int ks = rest & 7; rest >>= 3;
    int j = rest % 3; rest /= 3;
    int wv = rest & 15, cls = rest >> 4;
    int gate = (wv < 8) ? (j < 2 ? j : 4) : (j < 2 ? j + 2 : 5);  // {0,1,4} / {2,3,5}
    int n = gate * 128 + (wv & 7) * 16 + (lane & 15);
    int k = ks * 32 + ((lane >> 4) << 3);
    src = W_enc + (size_t)(cls * 768 + n) * 384 + k;
  } else if (idx < OFF_F3) {  // x-part Wx
    int f = idx - OFF_WX;
    int lane = (f >> 3) & 63, rest = f >> 9;
    int ks = rest & 3; rest >>= 2;
    int wv = rest & 7; rest >>= 3;
    int gate = rest % 6, cls = rest / 6;
    int n = gate * 128 + wv * 16 + (lane & 15);
    int k = 256 + ks * 32 + ((lane >> 4) << 3);
    src = W_enc + (size_t)(cls * 768 + n) * 384 + k;
  } else if (idx < OFF_F4) {  // fc3
    int f = idx - OFF_F3;
    int lane = (f >> 3) & 63, rest = f >> 9;
    int ks = rest & 1, wv = rest >> 1;
    int n = wv * 16 + (lane & 15), k = ks * 32 + ((lane >> 4) << 3);
    src = fc3_w + n * 64 + k;
  } else {  // fc4
    int f = idx - OFF_F4;
    int lane = (f >> 3) & 63, rest = f >> 9;
    int ks = rest & 3, wv = rest >> 2;
    int n = wv * 16 + (lane & 15), k = ks * 32 + ((lane >> 4) << 3);
    src = fc4_w + n * 128 + k;
  }
  f32x4 a = *(const f32x4*)src, b = *(const f32x4*)(src + 4);
  half8 h;
  h[0] = (hf)a.x; h[1] = (hf)a.y; h[2] = (hf)a.z; h[3] = (hf)a.w;
  h[4] = (hf)b.x; h[5] = (hf)b.y; h[6] = (hf)b.z; h[7] = (hf)b.w;
  *(half8*)&wsh[idx] = h;
}

// ---- kernel 2: FUSED prelude + recurrence. prelude kernel + xWb (75MB round trip)
// eliminated. Prologue: fc3+fc4 for this bn -> h in LDS (fp16, same precision path as
// the old prelude). Per step: recurrent GEMM (K=256) and x-gate GEMM (K=128, A-rows =
// h[cell(s,c16)], zero-row for inactive windows) ACCUMULATE INTO THE SAME acc[6];
// bias added at use, masked by okx && s<12 (== old actf*B baked semantics). Wx B-frags
// streamed from L2 per step in 3 batches of 2 gates (zk-dependent addr defeats LICM;
// caps reg pressure ~250). Everything else (owner update, col roll, bar_dep) = R12.
__global__ __launch_bounds__(512, 2) __attribute__((amdgpu_waves_per_eu(2, 2))) void witran(
    const hf* __restrict__ wsh, const float* __restrict__ x,
    const float* __restrict__ fc3_b, const float* __restrict__ fc4_b,
    const float* __restrict__ B_enc,
    const float* __restrict__ fc1_w, const float* __restrict__ fc1_b,
    const float* __restrict__ fc2_w, const float* __restrict__ fc2_b,
    float* __restrict__ out) {
  const int cls = blockIdx.x & 1, bn = blockIdx.x >> 1;
  const int t = threadIdx.x, lane = t & 63, wv = t >> 6;  // wv 0..7
  const int c16 = lane & 15, quad = lane >> 4;
  const int d = wv * 16 + c16;
  const bool act = (quad < 3);
  const int c0 = quad * 4;

  __shared__ __attribute__((aligned(16))) hf smem[SM_HALFS];

  // resident recurrent weights (R12 config): wf[0..2]=u_r,o_r,i_r; wf[3..4]=u_c,o_c;
  // i_c -> LDS (WL region, staged after prologue GEMMs free the R region)
  half8 wf[5][8];
  {
    const hf* wbR = wsh + ((size_t)((cls * 16 + wv) * 3) * 8) * 512 + lane * 8;
    const hf* wbC = wsh + ((size_t)((cls * 16 + 8 + wv) * 3) * 8) * 512 + lane * 8;
#pragma unroll
    for (int j = 0; j < 3; ++j)
#pragma unroll
      for (int ks = 0; ks < 8; ++ks)
        wf[j][ks] = *(const half8*)(wbR + (j * 8 + ks) * 512);
#pragma unroll
    for (int j = 0; j < 2; ++j)
#pragma unroll
      for (int ks = 0; ks < 8; ++ks)
        wf[3 + j][ks] = *(const half8*)(wbC + (j * 8 + ks) * 512);
  }
  // acc[j] <-> original gate G[j]; biases loaded once
  float bv[6];
  {
    const int G[6] = {0, 1, 4, 2, 3, 5};
#pragma unroll
    for (int j = 0; j < 6; ++j) bv[j] = B_enc[cls * 768 + G[j] * 128 + d];
  }

  // ---- prologue: stage x -> fp16 LDS; zero zrow ----
#pragma unroll
  for (int i = 0; i < 6; ++i) {
    int f = t * 4 + i * 2048;
    int r = f >> 6, cb = f & 63;
    f32x4 a = *(const f32x4*)(x + (size_t)(bn * 192 + r) * 64 + cb);
    half4 h4;
    h4[0] = (hf)a.x; h4[1] = (hf)a.y; h4[2] = (hf)a.z; h4[3] = (hf)a.w;
    *(half4*)&smem[XA_OFF + xidx(r, cb)] = h4;  // cb&7 in {0,4}: inside one 8-unit
  }
  if (t < 16) {  // zrow (h row 192): hidx(192,k) is linear
    half8 z = {};
    *(half8*)&smem[H_OFF + 192 * 128 + t * 8] = z;
  }
  __syncthreads();

  // fc3: xA -> hbuf1 (M=192, K=64)
  {
    float b3v = fc3_b[d];
    half8 w0 = *(const half8*)(wsh + OFF_F3 + (wv * 2 + 0) * 512 + lane * 8);
    half8 w1 = *(const half8*)(wsh + OFF_F3 + (wv * 2 + 1) * 512 + lane * 8);
#pragma unroll
    for (int mt = 0; mt < 12; ++mt) {
      f32x4 a = {0.f, 0.f, 0.f, 0.f};
      a = __builtin_amdgcn_mfma_f32_16x16x32_f16(
          *(const half8*)&smem[XA_OFF + xidx(mt * 16 + c16, quad * 8)], w0, a, 0, 0, 0);
      a = __builtin_amdgcn_mfma_f32_16x16x32_f16(
          *(const half8*)&smem[XA_OFF + xidx(mt * 16 + c16, 32 + quad * 8)], w1, a, 0, 0, 0);
#pragma unroll
      for (int r = 0; r < 4; ++r)
        smem[H1_OFF + hidx(mt * 16 + quad * 4 + r, d)] = (hf)fmaxf(a[r] + b3v, 0.f);
    }
  }
  __syncthreads();

  // fc4: hbuf1 -> h (M=192, K=128)
  {
    float b4v = fc4_b[d];
    half8 w4[4];
#pragma unroll
    for (int ks = 0; ks < 4; ++ks)
      w4[ks] = *(const half8*)(wsh + OFF_F4 + (wv * 4 + ks) * 512 + lane * 8);
#pragma unroll
    for (int mt = 0; mt < 12; ++mt) {
      f32x4 a = {0.f, 0.f, 0.f, 0.f};
#pragma unroll
      for (int ks = 0; ks < 4; ++ks)
        a = __builtin_amdgcn_mfma_f32_16x16x32_f16(
            *(const half8*)&smem[H1_OFF + hidx(mt * 16 + c16, ks * 32 + quad * 8)], w4[ks], a,
            0, 0, 0);
#pragma unroll
      for (int r = 0; r < 4; ++r)
        smem[H_OFF + hidx(mt * 16 + quad * 4 + r, d)] = (hf)(a[r] + b4v);
    }
  }
  __syncthreads();  // xA/hbuf1 dead; R region repurposed

  // zero A[0],A[1]; stage i_c Wrec frags into WL
  for (int i = t; i < 4096; i += 512) ((int*)&smem[A0_OFF])[i] = 0;
  {
    const hf* wbC = wsh + ((size_t)((cls * 16 + 8 + wv) * 3) * 8) * 512 + lane * 8;
#pragma unroll
    for (int ks = 0; ks < 8; ++ks)
      *(half8*)&smem[WL_OFF + wv * 4096 + ks * 512 + lane * 8] =
          *(const half8*)(wbC + (16 + ks) * 512);
  }

  // per-wave Wx base: frag(origG, ks) at wxs + origG*16384 + ks*512
  const hf* wxs = wsh + OFF_WX + (size_t)(cls * 48 + wv) * 2048 + lane * 8;

  float hr[4] = {0.f, 0.f, 0.f, 0.f};  // row holds: registers

  auto step = [&](int acof, int anof, int s, int zk_) -> int {
    const hf* Ac = smem + acof + zk_;
    hf* An = smem + anof + zk_;
    const hf* wxp = wxs + zk_;  // zk-dependent: re-loaded every step, not hoisted
    // batch-1 Wx (acc0=u_r g0, acc1=o_r g1); latency covered by recurrent GEMM
    half8 wxA[8];
#pragma unroll
    for (int ks = 0; ks < 4; ++ks) {
      wxA[ks] = *(const half8*)(wxp + 0 * 16384 + ks * 512);
      wxA[4 + ks] = *(const half8*)(wxp + 1 * 16384 + ks * 512);
    }
    // ---- recurrent GEMM: 6 gates x K=256 ----
    f32x4 acc[6];
#pragma unroll
    for (int g = 0; g < 6; ++g) acc[g] = (f32x4){0.f, 0.f, 0.f, 0.f};
#pragma unroll
    for (int ks = 0; ks < 8; ++ks) {
      half8 av = *(const half8*)&Ac[aidx(c16, ks * 32 + quad * 8)];
#pragma unroll
      for (int g = 0; g < 5; ++g)
        acc[g] = __builtin_amdgcn_mfma_f32_16x16x32_f16(av, wf[g][ks], acc[g], 0, 0, 0);
      half8 w5 = *(const half8*)&smem[WL_OFF + zk_ + wv * 4096 + ks * 512 + lane * 8];
      acc[5] = __builtin_amdgcn_mfma_f32_16x16x32_f16(av, w5, acc[5], 0, 0, 0);
    }
    // ---- x-part: A-rows = h[cell(s,c16)] (zrow when inactive), K=128 ----
    unsigned rrv = (unsigned)(s - c16);
    int cell = (c16 < 12 && rrv < 16u) ? (int)rrv * 12 + c16 : 192;
    half8 avx[4];
#pragma unroll
    for (int ks = 0; ks < 4; ++ks)
      avx[ks] = *(const half8*)&smem[H_OFF + hidx(cell, ks * 32 + quad * 8)];
#pragma unroll
    for (int ks = 0; ks < 4; ++ks)
      acc[0] = __builtin_amdgcn_mfma_f32_16x16x32_f16(avx[ks], wxA[ks], acc[0], 0, 0, 0);
#pragma unroll
    for (int ks = 0; ks < 4; ++ks)
      acc[1] = __builtin_amdgcn_mfma_f32_16x16x32_f16(avx[ks], wxA[4 + ks], acc[1], 0, 0, 0);
    // batch-2 (acc2=i_r g4, acc3=u_c g2)
    half8 wxB[8];
#pragma unroll
    for (int ks = 0; ks < 4; ++ks) {
      wxB[ks] = *(const half8*)(wxp + 4 * 16384 + ks * 512);
      wxB[4 + ks] = *(const half8*)(wxp + 2 * 16384 + ks * 512);
    }
#pragma unroll
    for (int ks = 0; ks < 4; ++ks)
      acc[2] = __builtin_amdgcn_mfma_f32_16x16x32_f16(avx[ks], wxB[ks], acc[2], 0, 0, 0);
#pragma unroll
    for (int ks = 0; ks < 4; ++ks)
      acc[3] = __builtin_amdgcn_mfma_f32_16x16x32_f16(avx[ks], wxB[4 + ks], acc[3], 0, 0, 0);
    // batch-3 (acc4=o_c g3, acc5=i_c g5)
    half8 wxC[8];
#pragma unroll
    for (int ks = 0; ks < 4; ++ks) {
      wxC[ks] = *(const half8*)(wxp + 3 * 16384 + ks * 512);
      wxC[4 + ks] = *(const half8*)(wxp + 5 * 16384 + ks * 512);
    }
#pragma unroll
    for (int ks = 0; ks < 4; ++ks)
      acc[4] = __builtin_amdgcn_mfma_f32_16x16x32_f16(avx[ks], wxC[ks], acc[4], 0, 0, 0);
#pragma unroll
    for (int ks = 0; ks < 4; ++ks)
      acc[5] = __builtin_amdgcn_mfma_f32_16x16x32_f16(avx[ks], wxC[4 + ks], acc[5], 0, 0, 0);
    // ---- owner update: bias masked by okx && s<12; x-part already zero via zrow ----
    if (act) {
      float hcold[4];
#pragma unroll
      for (int r = 0; r < 4; ++r) hcold[r] = (float)Ac[aidx(c0 + r, 128 + d)];
#pragma unroll
      for (int r = 0; r < 4; ++r) {
        int c = c0 + r;
        bool okx = ((unsigned)(s - c) < 16u);
        float bm = (okx && s < 12) ? 1.f : 0.f;
        float uu = sigmoidf_(acc[0][r] + bm * bv[0]);
        float oo = sigmoidf_(acc[1][r] + bm * bv[1]);
        float ii = tanh_(acc[2][r] + bm * bv[2]);
        float h1 = tanh_(hr[r] + uu * (ii - hr[r])) * oo;
        hr[r] = h1;
        An[aidx(c, d)] = (hf)h1;
        float u2 = sigmoidf_(acc[3][r] + bm * bv[3]);
        float o2 = sigmoidf_(acc[4][r] + bm * bv[4]);
        float i2 = tanh_(acc[5][r] + bm * bv[5]);
        float h2 = tanh_(hcold[r] + u2 * (i2 - hcold[r])) * o2;
        int cw = (c == 11) ? 0 : c + 1;  // col roll: h_col[c] feeds slice c+1
        An[aidx(cw, 128 + d)] = (hf)h2;
      }
    }
    return bar_dep();  // An complete; lgkm only (vmcnt in flight)
  };

  int zk = bar_dep();  // A zero + WL + h visible

#pragma unroll 1
  for (int s = 0; s < Steps - 1; s += 2) {
    zk = step(A0_OFF, A1_OFF, s, zk);
    zk = step(A1_OFF, A0_OFF, s + 1, zk);
  }
  zk = step(A0_OFF, A1_OFF, Steps - 1, zk);  // step 26: A[0] -> A[1]

  // ---- epilogue: h_row[11] at A[1][11][0:128); rolled h_col[11] at A[1][0][128:256) ----
  const hf* Af = smem + A1_OFF + zk;
  float* red = (float*)&smem[H_OFF];  // h dead; alias
  if (t < 128) {
    float hrv = (float)Af[aidx(11, t)];
    float hcv = (float)Af[aidx(0, 128 + t)];
    red[t] = 0.5f * (hcv * fc1_w[cls * 128 + t] + hrv * fc2_w[cls * 128 + t]);
  }
  __syncthreads();
  if (t == 0) {
    float sum = 0.f;
    for (int i = 0; i < 128; ++i) sum += red[i];
    out[bn * 2 + cls] = sum + 0.5f * (fc1_b[cls] + fc2_b[cls]);
  }
}

extern "C" void kernel_launch(void* const* d_in, const int* in_sizes, int n_in,
                              void* d_out, int out_size, void* d_ws, size_t ws_size,
                              hipStream_t stream) {
  const float* x = (const float*)d_in[0];
  // d_in[1] = pad_mask: unused by the reference
  const float* fc3_w = (const float*)d_in[2];
  const float* fc3_b = (const float*)d_in[3];
  const float* fc4_w = (const float*)d_in[4];
  const float* fc4_b = (const float*)d_in[5];
  const float* W_enc = (const float*)d_in[6];
  const float* B_enc = (const float*)d_in[7];
  const float* fc1_w = (const float*)d_in[8];
  const float* fc1_b = (const float*)d_in[9];
  const float* fc2_w = (const float*)d_in[10];
  const float* fc2_b = (const float*)d_in[11];
  float* out = (float*)d_out;

  hf* wsh = (hf*)d_ws;  // frag tables 1,228,800 B (xWb eliminated)

  prep<<<dim3(150), dim3(512), 0, stream>>>(fc3_w, fc4_w, W_enc, wsh);
  witran<<<dim3(128), dim3(512), 0, stream>>>(wsh, x, fc3_b, fc4_b, B_enc,
                                              fc1_w, fc1_b, fc2_w, fc2_b, out);
}